// Round 5
// baseline (197.398 us; speedup 1.0000x reference)
//
#include <hip/hip_runtime.h>
#include <hip/hip_bf16.h>
#include <math.h>

#define BB 32
#define TT 4096
#define NN 11
#define FF 16
#define HH 32
#define LN_EPS 1e-5f

// v10 = v7 per-wave structure, bigger blocks: 512 threads = 128 tokens x 4 f-chunks.
// 1024 blocks total (was 2048): R1-R4 showed measured occupancy tracks per-block
// lifetime, not static limits -> dispatch-rate-capped residency. Fewer/longer blocks
// raise resident waves without touching the (verified) per-wave math.
// Wave wv (0..7) owns tokens [16wv,16wv+16) -> LDS rows [176wv,176wv+176) -> 11 tiles.
#define TOKENS_PER_BLOCK 128
#define NBLOCKS (BB * TT / TOKENS_PER_BLOCK)          // 1024
#define BLOCKS_PER_BATCH (TT / TOKENS_PER_BLOCK)      // 32 (exact) -> lab uniform
#define ROW_STRIDE_B 32                               // exactly 16 bf16; 45056 B LDS

typedef __attribute__((ext_vector_type(8))) short short8;  // 8 bf16 = 4 VGPRs
typedef __attribute__((ext_vector_type(4))) float f32x4;

union Frag { unsigned u[4]; uint4 u4; short8 v; };

__device__ __forceinline__ unsigned pack2_bf16(float a, float b) {
    __hip_bfloat162 p = __float22bfloat162_rn(make_float2(a, b));
    union { __hip_bfloat162 h; unsigned u; } cvt; cvt.h = p; return cvt.u;
}

// tanh-form GELU via sigmoid; max dev from exact-erf GELU ~3e-3
__device__ __forceinline__ float fast_gelu(float v) {
    const float v2 = v * v;
    const float c  = fmaf(0.044715f, v2, 1.0f);
    const float t  = v * c * 1.5957691216057308f;
    const float e  = __expf(-t);
    return v * __builtin_amdgcn_rcpf(1.0f + e);
}

__global__ __launch_bounds__(512) void fused_v10(
    const float* __restrict__ x,        // [B,T,N,F]
    const int*   __restrict__ lab_idx,  // [B]
    const float* __restrict__ proj,     // [L,N,N]
    const float* __restrict__ bias,     // [L,1,N,F]
    const float* __restrict__ w1,       // [F,H]
    const float* __restrict__ b1,       // [H]
    const float* __restrict__ ln_g,     // [H]
    const float* __restrict__ ln_b,     // [H]
    const float* __restrict__ w2,       // [H,F]
    const float* __restrict__ b2,       // [F]
    float*       __restrict__ out)      // [B,T,N,F]
{
    // 1408 rows x 32 B = 45056 B. Row r = tl*11 + m (token-major, matches out order).
    __shared__ __align__(16) unsigned char o_st[1408 * ROW_STRIDE_B];

    const int tid  = threadIdx.x;
    const int wv   = tid >> 6;
    const int lane = tid & 63;
    const int q    = lane >> 4;
    const int c    = lane & 15;
    const int tl   = tid >> 2;          // token-local 0..127
    const int f4   = tid & 3;           // f-chunk 0..3

    const int token = blockIdx.x * TOKENS_PER_BLOCK + tl;
    const int lab   = lab_idx[blockIdx.x / BLOCKS_PER_BATCH];   // block-uniform -> SGPR

    // ---------- projection: m-outer, 4-reg accumulator, fused LDS staging ----------
    // x read exactly once per element (disjoint across threads), weights uniform (SGPR).
    const float4* xb = reinterpret_cast<const float4*>(x)    + (size_t)token * (NN * FF / 4) + f4;
    const float4* bb = reinterpret_cast<const float4*>(bias) + (size_t)lab   * (NN * FF / 4) + f4;
    const float*  Wl = proj + (size_t)lab * (NN * NN);       // uniform base -> s_load

    float4 xv[NN];
    #pragma unroll
    for (int n = 0; n < NN; ++n) xv[n] = xb[4 * n];

    unsigned char* orow = &o_st[(tl * NN) * ROW_STRIDE_B + f4 * 8];
    #pragma unroll
    for (int m = 0; m < NN; ++m) {
        const float4 bv = bb[4 * m];
        float o0 = bv.x, o1 = bv.y, o2 = bv.z, o3 = bv.w;
        #pragma unroll
        for (int n = 0; n < NN; ++n) {
            const float wm = Wl[n * NN + m];   // uniform -> SGPR operand
            o0 = fmaf(xv[n].x, wm, o0);
            o1 = fmaf(xv[n].y, wm, o1);
            o2 = fmaf(xv[n].z, wm, o2);
            o3 = fmaf(xv[n].w, wm, o3);
        }
        uint2 p;
        p.x = pack2_bf16(o0, o1);
        p.y = pack2_bf16(o2, o3);
        *reinterpret_cast<uint2*>(orow + m * ROW_STRIDE_B) = p;
    }
    // no __syncthreads: rows [176wv,176wv+176) were written by this wave's own lanes;
    // same-wave LDS ops are pipe-ordered.

    // ---------- weight fragments as A-operands (verified in R4) ----------
    Frag a1c0, a1c1, a2f;
    #pragma unroll
    for (int d = 0; d < 4; ++d) {
        const int k0 = 8 * q + 2 * d;
        float wa0 = 0.f, wa1 = 0.f, wb0 = 0.f, wb1 = 0.f;
        if (q < 2) {
            wa0 = w1[k0 * HH + c];       wa1 = w1[(k0 + 1) * HH + c];
            wb0 = w1[k0 * HH + 16 + c];  wb1 = w1[(k0 + 1) * HH + 16 + c];
        }
        a1c0.u[d] = pack2_bf16(wa0, wa1);
        a1c1.u[d] = pack2_bf16(wb0, wb1);
        a2f.u[d]  = pack2_bf16(w2[k0 * FF + c], w2[(k0 + 1) * FF + c]);
    }

    float4 b1v0 = *reinterpret_cast<const float4*>(b1 + 4 * q);
    float4 b1v1 = *reinterpret_cast<const float4*>(b1 + 16 + 4 * q);
    float4 b2v  = *reinterpret_cast<const float4*>(b2 + 4 * q);
    float4 g0   = *reinterpret_cast<const float4*>(ln_g + 4 * q);
    float4 g1   = *reinterpret_cast<const float4*>(ln_g + 16 + 4 * q);
    float4 e0   = *reinterpret_cast<const float4*>(ln_b + 4 * q);
    float4 e1   = *reinterpret_cast<const float4*>(ln_b + 16 + 4 * q);
    float g0a[4] = {g0.x, g0.y, g0.z, g0.w}, g1a[4] = {g1.x, g1.y, g1.z, g1.w};
    float e0a[4] = {e0.x, e0.y, e0.z, e0.w}, e1a[4] = {e1.x, e1.y, e1.z, e1.w};
    float b1a0[4] = {b1v0.x, b1v0.y, b1v0.z, b1v0.w};
    float b1a1[4] = {b1v1.x, b1v1.y, b1v1.z, b1v1.w};
    float b2a[4]  = {b2v.x, b2v.y, b2v.z, b2v.w};

    const size_t outrow0 = (size_t)blockIdx.x * (TOKENS_PER_BLOCK * NN) + wv * 176;
    const int srcA = (q & 1) * 32 + c;
    const int srcB = srcA + 16;

    #pragma unroll
    for (int t = 0; t < NN; ++t) {
        // ---- GEMM1 (transposed): B1[k=f=8q+j][col=c] = o_bf16[row 176wv+16t+c][f]
        Frag B1;
        B1.u4 = *reinterpret_cast<const uint4*>(
            &o_st[(176 * wv + 16 * t + c) * ROW_STRIDE_B + (q & 1) * 16]);

        f32x4 accA = { b1a0[0], b1a0[1], b1a0[2], b1a0[3] };
        f32x4 accB = { b1a1[0], b1a1[1], b1a1[2], b1a1[3] };
        accA = __builtin_amdgcn_mfma_f32_16x16x32_bf16(a1c0.v, B1.v, accA, 0, 0, 0);
        accB = __builtin_amdgcn_mfma_f32_16x16x32_bf16(a1c1.v, B1.v, accB, 0, 0, 0);

        // ---- LayerNorm over H=32 (column c's values live in lanes c, c+16, c+32, c+48)
        float s = 0.f, ss = 0.f;
        #pragma unroll
        for (int i = 0; i < 4; ++i) {
            s += accA[i] + accB[i];
            ss = fmaf(accA[i], accA[i], ss);
            ss = fmaf(accB[i], accB[i], ss);
        }
        s  += __shfl_xor(s, 16, 64);  s  += __shfl_xor(s, 32, 64);
        ss += __shfl_xor(ss, 16, 64); ss += __shfl_xor(ss, 32, 64);
        const float mu   = s * (1.f / HH);
        const float var  = ss * (1.f / HH) - mu * mu;
        const float rstd = rsqrtf(var + LN_EPS);
        const float nb   = -mu * rstd;

        // ---- affine + GELU
        float ga[4], gb[4];
        #pragma unroll
        for (int i = 0; i < 4; ++i) {
            ga[i] = fast_gelu(fmaf(fmaf(accA[i], rstd, nb), g0a[i], e0a[i]));
            gb[i] = fast_gelu(fmaf(fmaf(accB[i], rstd, nb), g1a[i], e1a[i]));
        }
        const unsigned c0d0 = pack2_bf16(ga[0], ga[1]);
        const unsigned c0d1 = pack2_bf16(ga[2], ga[3]);
        const unsigned c1d0 = pack2_bf16(gb[0], gb[1]);
        const unsigned c1d1 = pack2_bf16(gb[2], gb[3]);

        // ---- register transpose to B2-frag (verified in R4)
        Frag B2;
        {
            unsigned lo, hi;
            lo = __shfl((int)c0d0, srcA, 64); hi = __shfl((int)c1d0, srcA, 64);
            B2.u[0] = (q < 2) ? lo : hi;
            lo = __shfl((int)c0d1, srcA, 64); hi = __shfl((int)c1d1, srcA, 64);
            B2.u[1] = (q < 2) ? lo : hi;
            lo = __shfl((int)c0d0, srcB, 64); hi = __shfl((int)c1d0, srcB, 64);
            B2.u[2] = (q < 2) ? lo : hi;
            lo = __shfl((int)c0d1, srcB, 64); hi = __shfl((int)c1d1, srcB, 64);
            B2.u[3] = (q < 2) ? lo : hi;
        }

        // ---- GEMM2 (transposed, K=32): out^T[f=4q+i][col=c]
        f32x4 acc2 = { b2a[0], b2a[1], b2a[2], b2a[3] };
        acc2 = __builtin_amdgcn_mfma_f32_16x16x32_bf16(a2f.v, B2.v, acc2, 0, 0, 0);

        // ---- contiguous float4 store: row = outrow0 + 16t + c, f = 4q..4q+3
        float4* dst = reinterpret_cast<float4*>(out + (outrow0 + 16 * t + c) * FF + 4 * q);
        *dst = make_float4(acc2[0], acc2[1], acc2[2], acc2[3]);
    }
}

extern "C" void kernel_launch(void* const* d_in, const int* in_sizes, int n_in,
                              void* d_out, int out_size, void* d_ws, size_t ws_size,
                              hipStream_t stream) {
    const float* x       = (const float*)d_in[0];
    const int*   lab_idx = (const int*)  d_in[1];
    const float* proj    = (const float*)d_in[2];
    const float* bias    = (const float*)d_in[3];
    const float* w1      = (const float*)d_in[4];
    const float* b1      = (const float*)d_in[5];
    const float* ln_g    = (const float*)d_in[6];
    const float* ln_b    = (const float*)d_in[7];
    const float* w2      = (const float*)d_in[8];
    const float* b2      = (const float*)d_in[9];
    float* out = (float*)d_out;

    fused_v10<<<NBLOCKS, 512, 0, stream>>>(
        x, lab_idx, proj, bias, w1, b1, ln_g, ln_b, w2, b2, out);
}

// Round 8
// 190.742 us; speedup vs baseline: 1.0349x; 1.0349x over previous
//
#include <hip/hip_runtime.h>
#include <hip/hip_bf16.h>
#include <math.h>

#define BB 32
#define TT 4096
#define NN 11
#define FF 16
#define HH 32
#define LN_EPS 1e-5f

// v11b = v7 (best: 67.6us) + non-temporal out-stores (fixed: ext_vector_type for builtin).
// R1-R5: dur invariant under occupancy/code/crossbar changes; FETCH_SIZE == x/2
// every round -> out's write-allocate stream evicts x from L3 + HBM R/W turnaround.
// out is never read: nt-store keeps x L3-resident and unmixes the HBM streams.
#define TOKENS_PER_BLOCK 64
#define NBLOCKS (BB * TT / TOKENS_PER_BLOCK)          // 2048
#define BLOCKS_PER_BATCH (TT / TOKENS_PER_BLOCK)      // 64 (exact) -> lab uniform
#define ROW_STRIDE_B 32                               // exactly 16 bf16; 22528 B LDS -> 7 blocks/CU

typedef __attribute__((ext_vector_type(8))) short short8;  // 8 bf16 = 4 VGPRs
typedef __attribute__((ext_vector_type(4))) float f32x4;

union Frag { unsigned u[4]; uint4 u4; short8 v; };

__device__ __forceinline__ unsigned pack2_bf16(float a, float b) {
    __hip_bfloat162 p = __float22bfloat162_rn(make_float2(a, b));
    union { __hip_bfloat162 h; unsigned u; } cvt; cvt.h = p; return cvt.u;
}

// tanh-form GELU via sigmoid; max dev from exact-erf GELU ~3e-3
__device__ __forceinline__ float fast_gelu(float v) {
    const float v2 = v * v;
    const float c  = fmaf(0.044715f, v2, 1.0f);
    const float t  = v * c * 1.5957691216057308f;
    const float e  = __expf(-t);
    return v * __builtin_amdgcn_rcpf(1.0f + e);
}

__global__ __launch_bounds__(256) void fused_v11b(
    const float* __restrict__ x,        // [B,T,N,F]
    const int*   __restrict__ lab_idx,  // [B]
    const float* __restrict__ proj,     // [L,N,N]
    const float* __restrict__ bias,     // [L,1,N,F]
    const float* __restrict__ w1,       // [F,H]
    const float* __restrict__ b1,       // [H]
    const float* __restrict__ ln_g,     // [H]
    const float* __restrict__ ln_b,     // [H]
    const float* __restrict__ w2,       // [H,F]
    const float* __restrict__ b2,       // [F]
    float*       __restrict__ out)      // [B,T,N,F]
{
    // 704 rows x 32 B = 22528 B. Row r = tl*11 + m (token-major, matches out order).
    __shared__ __align__(16) unsigned char o_st[704 * ROW_STRIDE_B];

    const int tid  = threadIdx.x;
    const int wv   = tid >> 6;
    const int lane = tid & 63;
    const int q    = lane >> 4;
    const int c    = lane & 15;
    const int tl   = tid >> 2;          // token-local 0..63
    const int f4   = tid & 3;           // f-chunk 0..3

    const int token = blockIdx.x * TOKENS_PER_BLOCK + tl;
    const int lab   = lab_idx[blockIdx.x / BLOCKS_PER_BATCH];   // block-uniform -> SGPR

    // ---------- projection: m-outer, 4-reg accumulator, fused LDS staging ----------
    // x read exactly once per element (disjoint across threads), weights uniform (SGPR).
    const float4* xb = reinterpret_cast<const float4*>(x)    + (size_t)token * (NN * FF / 4) + f4;
    const float4* bb = reinterpret_cast<const float4*>(bias) + (size_t)lab   * (NN * FF / 4) + f4;
    const float*  Wl = proj + (size_t)lab * (NN * NN);       // uniform base -> s_load

    float4 xv[NN];
    #pragma unroll
    for (int n = 0; n < NN; ++n) xv[n] = xb[4 * n];

    unsigned char* orow = &o_st[(tl * NN) * ROW_STRIDE_B + f4 * 8];
    #pragma unroll
    for (int m = 0; m < NN; ++m) {
        const float4 bv = bb[4 * m];
        float o0 = bv.x, o1 = bv.y, o2 = bv.z, o3 = bv.w;
        #pragma unroll
        for (int n = 0; n < NN; ++n) {
            const float wm = Wl[n * NN + m];   // uniform -> SGPR operand
            o0 = fmaf(xv[n].x, wm, o0);
            o1 = fmaf(xv[n].y, wm, o1);
            o2 = fmaf(xv[n].z, wm, o2);
            o3 = fmaf(xv[n].w, wm, o3);
        }
        uint2 p;
        p.x = pack2_bf16(o0, o1);
        p.y = pack2_bf16(o2, o3);
        *reinterpret_cast<uint2*>(orow + m * ROW_STRIDE_B) = p;
    }
    // no __syncthreads: rows [176wv,176wv+176) were written by this wave's own lanes;
    // same-wave LDS ops are pipe-ordered.

    // ---------- weight fragments as A-operands (verified in R4) ----------
    Frag a1c0, a1c1, a2f;
    #pragma unroll
    for (int d = 0; d < 4; ++d) {
        const int k0 = 8 * q + 2 * d;
        float wa0 = 0.f, wa1 = 0.f, wb0 = 0.f, wb1 = 0.f;
        if (q < 2) {
            wa0 = w1[k0 * HH + c];       wa1 = w1[(k0 + 1) * HH + c];
            wb0 = w1[k0 * HH + 16 + c];  wb1 = w1[(k0 + 1) * HH + 16 + c];
        }
        a1c0.u[d] = pack2_bf16(wa0, wa1);
        a1c1.u[d] = pack2_bf16(wb0, wb1);
        a2f.u[d]  = pack2_bf16(w2[k0 * FF + c], w2[(k0 + 1) * FF + c]);
    }

    float4 b1v0 = *reinterpret_cast<const float4*>(b1 + 4 * q);
    float4 b1v1 = *reinterpret_cast<const float4*>(b1 + 16 + 4 * q);
    float4 b2v  = *reinterpret_cast<const float4*>(b2 + 4 * q);
    float4 g0   = *reinterpret_cast<const float4*>(ln_g + 4 * q);
    float4 g1   = *reinterpret_cast<const float4*>(ln_g + 16 + 4 * q);
    float4 e0   = *reinterpret_cast<const float4*>(ln_b + 4 * q);
    float4 e1   = *reinterpret_cast<const float4*>(ln_b + 16 + 4 * q);
    float g0a[4] = {g0.x, g0.y, g0.z, g0.w}, g1a[4] = {g1.x, g1.y, g1.z, g1.w};
    float e0a[4] = {e0.x, e0.y, e0.z, e0.w}, e1a[4] = {e1.x, e1.y, e1.z, e1.w};
    float b1a0[4] = {b1v0.x, b1v0.y, b1v0.z, b1v0.w};
    float b1a1[4] = {b1v1.x, b1v1.y, b1v1.z, b1v1.w};
    float b2a[4]  = {b2v.x, b2v.y, b2v.z, b2v.w};

    const size_t outrow0 = (size_t)blockIdx.x * (TOKENS_PER_BLOCK * NN) + wv * 176;
    const int srcA = (q & 1) * 32 + c;
    const int srcB = srcA + 16;

    #pragma unroll
    for (int t = 0; t < NN; ++t) {
        // ---- GEMM1 (transposed): B1[k=f=8q+j][col=c] = o_bf16[row 176wv+16t+c][f]
        Frag B1;
        B1.u4 = *reinterpret_cast<const uint4*>(
            &o_st[(176 * wv + 16 * t + c) * ROW_STRIDE_B + (q & 1) * 16]);

        f32x4 accA = { b1a0[0], b1a0[1], b1a0[2], b1a0[3] };
        f32x4 accB = { b1a1[0], b1a1[1], b1a1[2], b1a1[3] };
        accA = __builtin_amdgcn_mfma_f32_16x16x32_bf16(a1c0.v, B1.v, accA, 0, 0, 0);
        accB = __builtin_amdgcn_mfma_f32_16x16x32_bf16(a1c1.v, B1.v, accB, 0, 0, 0);

        // ---- LayerNorm over H=32 (column c's values live in lanes c, c+16, c+32, c+48)
        float s = 0.f, ss = 0.f;
        #pragma unroll
        for (int i = 0; i < 4; ++i) {
            s += accA[i] + accB[i];
            ss = fmaf(accA[i], accA[i], ss);
            ss = fmaf(accB[i], accB[i], ss);
        }
        s  += __shfl_xor(s, 16, 64);  s  += __shfl_xor(s, 32, 64);
        ss += __shfl_xor(ss, 16, 64); ss += __shfl_xor(ss, 32, 64);
        const float mu   = s * (1.f / HH);
        const float var  = ss * (1.f / HH) - mu * mu;
        const float rstd = rsqrtf(var + LN_EPS);
        const float nb   = -mu * rstd;

        // ---- affine + GELU
        float ga[4], gb[4];
        #pragma unroll
        for (int i = 0; i < 4; ++i) {
            ga[i] = fast_gelu(fmaf(fmaf(accA[i], rstd, nb), g0a[i], e0a[i]));
            gb[i] = fast_gelu(fmaf(fmaf(accB[i], rstd, nb), g1a[i], e1a[i]));
        }
        const unsigned c0d0 = pack2_bf16(ga[0], ga[1]);
        const unsigned c0d1 = pack2_bf16(ga[2], ga[3]);
        const unsigned c1d0 = pack2_bf16(gb[0], gb[1]);
        const unsigned c1d1 = pack2_bf16(gb[2], gb[3]);

        // ---- register transpose to B2-frag (verified in R4)
        Frag B2;
        {
            unsigned lo, hi;
            lo = __shfl((int)c0d0, srcA, 64); hi = __shfl((int)c1d0, srcA, 64);
            B2.u[0] = (q < 2) ? lo : hi;
            lo = __shfl((int)c0d1, srcA, 64); hi = __shfl((int)c1d1, srcA, 64);
            B2.u[1] = (q < 2) ? lo : hi;
            lo = __shfl((int)c0d0, srcB, 64); hi = __shfl((int)c1d0, srcB, 64);
            B2.u[2] = (q < 2) ? lo : hi;
            lo = __shfl((int)c0d1, srcB, 64); hi = __shfl((int)c1d1, srcB, 64);
            B2.u[3] = (q < 2) ? lo : hi;
        }

        // ---- GEMM2 (transposed, K=32): out^T[f=4q+i][col=c]
        f32x4 acc2 = { b2a[0], b2a[1], b2a[2], b2a[3] };
        acc2 = __builtin_amdgcn_mfma_f32_16x16x32_bf16(a2f.v, B2.v, acc2, 0, 0, 0);

        // ---- contiguous NON-TEMPORAL store (ext_vector f32x4 satisfies the builtin):
        // out is never read -> don't allocate in L2/L3 (keeps x resident, unmixes HBM streams).
        f32x4* dst = reinterpret_cast<f32x4*>(out + (outrow0 + 16 * t + c) * FF + 4 * q);
        __builtin_nontemporal_store(acc2, dst);
    }
}

extern "C" void kernel_launch(void* const* d_in, const int* in_sizes, int n_in,
                              void* d_out, int out_size, void* d_ws, size_t ws_size,
                              hipStream_t stream) {
    const float* x       = (const float*)d_in[0];
    const int*   lab_idx = (const int*)  d_in[1];
    const float* proj    = (const float*)d_in[2];
    const float* bias    = (const float*)d_in[3];
    const float* w1      = (const float*)d_in[4];
    const float* b1      = (const float*)d_in[5];
    const float* ln_g    = (const float*)d_in[6];
    const float* ln_b    = (const float*)d_in[7];
    const float* w2      = (const float*)d_in[8];
    const float* b2      = (const float*)d_in[9];
    float* out = (float*)d_out;

    fused_v11b<<<NBLOCKS, 256, 0, stream>>>(
        x, lab_idx, proj, bias, w1, b1, ln_g, ln_b, w2, b2, out);
}